// Round 1
// baseline (71.776 us; speedup 1.0000x reference)
//
#include <hip/hip_runtime.h>

// Exponential smoothing: out[b,j,h,d] = w^(j+1)*v0[h,d]
//                                     + (1-w) * sum_{k<=j} w^(j-k) * values[b,k,h,d]
// w = sigmoid(smoothing_weight[h]).  Equivalent recurrence:
//   s[-1] = v0;  s[j] = w*s[j-1] + (1-w)*x[j];  out[j] = s[j]
// Implemented as a 3-pass chunked parallel scan over t.

namespace {

constexpr int Bt = 16;    // batch
constexpr int Tt = 4096;  // time
constexpr int Ht = 8;     // heads
constexpr int Dt = 64;    // dim
constexpr int HD = Ht * Dt;   // 512 channels per batch (contiguous at fixed t)
constexpr int CL = 64;        // chunk length along t
constexpr int NC = Tt / CL;   // 64 chunks

__device__ __forceinline__ float sigmoidf_(float x) {
    return 1.0f / (1.0f + expf(-x));
}

// Pass 1: per (b, chunk) block of 512 threads, compute chunk-local scan end
// state (zero initial state).  Reads values coalesced (512 consecutive floats
// per time step).
__global__ __launch_bounds__(HD) void ema_pass1(
    const float* __restrict__ values, const float* __restrict__ sw,
    float* __restrict__ endstate) {
    const int blk = blockIdx.x;
    const int b = blk % Bt;
    const int c = blk / Bt;
    const int hd = threadIdx.x;          // h*64 + d
    const float w = sigmoidf_(sw[hd >> 6]);
    const float omw = 1.0f - w;

    const float* p = values + ((size_t)b * Tt + (size_t)c * CL) * HD + hd;
    float s = 0.0f;
    for (int j0 = 0; j0 < CL; j0 += 8) {
        float x[8];
        #pragma unroll
        for (int u = 0; u < 8; ++u) x[u] = p[(size_t)(j0 + u) * HD];
        #pragma unroll
        for (int u = 0; u < 8; ++u) s = fmaf(w, s, omw * x[u]);
    }
    endstate[(size_t)c * (Bt * HD) + b * HD + hd] = s;
}

// Pass 2: serial combine across chunks (tiny: 8192 threads x 64 iters).
// carry[c] = state entering chunk c;  carry[0] = v0.
__global__ __launch_bounds__(HD) void ema_pass2(
    const float* __restrict__ sw, const float* __restrict__ v0,
    const float* __restrict__ endstate, float* __restrict__ carry) {
    const int ch = blockIdx.x * blockDim.x + threadIdx.x;  // [0, Bt*HD)
    const int hd = ch & (HD - 1);
    const float w = sigmoidf_(sw[hd >> 6]);
    float Wc = w;
    #pragma unroll
    for (int i = 0; i < 6; ++i) Wc *= Wc;   // w^64 == w^CL
    float s = v0[hd];
    for (int c = 0; c < NC; ++c) {
        carry[(size_t)c * (Bt * HD) + ch] = s;
        s = fmaf(Wc, s, endstate[(size_t)c * (Bt * HD) + ch]);
    }
}

// Pass 3: redo the chunk scan seeded with the carry; write outputs.
__global__ __launch_bounds__(HD) void ema_pass3(
    const float* __restrict__ values, const float* __restrict__ sw,
    const float* __restrict__ carry, float* __restrict__ out) {
    const int blk = blockIdx.x;
    const int b = blk % Bt;
    const int c = blk / Bt;
    const int hd = threadIdx.x;
    const float w = sigmoidf_(sw[hd >> 6]);
    const float omw = 1.0f - w;

    const size_t base = ((size_t)b * Tt + (size_t)c * CL) * HD + hd;
    const float* p = values + base;
    float* q = out + base;
    float s = carry[(size_t)c * (Bt * HD) + b * HD + hd];
    for (int j0 = 0; j0 < CL; j0 += 8) {
        float x[8];
        #pragma unroll
        for (int u = 0; u < 8; ++u) x[u] = p[(size_t)(j0 + u) * HD];
        #pragma unroll
        for (int u = 0; u < 8; ++u) {
            s = fmaf(w, s, omw * x[u]);
            q[(size_t)(j0 + u) * HD] = s;
        }
    }
}

}  // namespace

extern "C" void kernel_launch(void* const* d_in, const int* in_sizes, int n_in,
                              void* d_out, int out_size, void* d_ws, size_t ws_size,
                              hipStream_t stream) {
    const float* values = (const float*)d_in[0];   // [16, 4096, 8, 64]
    const float* sw     = (const float*)d_in[1];   // [8, 1]
    const float* v0     = (const float*)d_in[2];   // [1, 1, 8, 64]
    float* out = (float*)d_out;

    float* endstate = (float*)d_ws;                            // NC*Bt*HD f32 = 2 MiB
    float* carry    = endstate + (size_t)NC * Bt * HD;         // another 2 MiB

    ema_pass1<<<dim3(NC * Bt), dim3(HD), 0, stream>>>(values, sw, endstate);
    ema_pass2<<<dim3(Bt), dim3(HD), 0, stream>>>(sw, v0, endstate, carry);
    ema_pass3<<<dim3(NC * Bt), dim3(HD), 0, stream>>>(values, sw, carry, out);
}